// Round 2
// baseline (279.418 us; speedup 1.0000x reference)
//
#include <hip/hip_runtime.h>

#define ERROR_OK 0.1f

constexpr int BLOCK  = 256;
constexpr int GRID   = 2048;   // 2048*256 = 524288 threads = 8192 waves = HW cap
constexpr int UNROLL = 4;      // 8 independent 16B loads in flight per thread

// Stage 1: grid-stride float4 streaming, unrolled x4 for memory-level
// parallelism (VGPR=12 at unroll 1 -> only 2 loads outstanding, latency-bound).
__global__ __launch_bounds__(BLOCK) void dz_partial_kernel(
    const float4* __restrict__ a,
    const float4* __restrict__ b,
    float* __restrict__ partials,
    int n4)
{
    const int tid    = blockIdx.x * BLOCK + threadIdx.x;
    const int stride = GRID * BLOCK;

    float acc[UNROLL];
    #pragma unroll
    for (int k = 0; k < UNROLL; ++k) acc[k] = 0.0f;

    int i = tid;
    // main unrolled body: issue all 2*UNROLL loads before any use
    for (; i + (UNROLL - 1) * stride < n4; i += UNROLL * stride) {
        float4 va[UNROLL], vb[UNROLL];
        #pragma unroll
        for (int k = 0; k < UNROLL; ++k) va[k] = a[i + k * stride];
        #pragma unroll
        for (int k = 0; k < UNROLL; ++k) vb[k] = b[i + k * stride];
        #pragma unroll
        for (int k = 0; k < UNROLL; ++k) {
            float d0 = va[k].x - vb[k].x;
            float d1 = va[k].y - vb[k].y;
            float d2 = va[k].z - vb[k].z;
            float d3 = va[k].w - vb[k].w;
            d0 = (fabsf(d0) < ERROR_OK) ? 0.0f : d0;
            d1 = (fabsf(d1) < ERROR_OK) ? 0.0f : d1;
            d2 = (fabsf(d2) < ERROR_OK) ? 0.0f : d2;
            d3 = (fabsf(d3) < ERROR_OK) ? 0.0f : d3;
            acc[k] += d0 * d0 + d1 * d1 + d2 * d2 + d3 * d3;
        }
    }
    // tail (not hit for N=2^25, kept for generality)
    for (; i < n4; i += stride) {
        float4 va = a[i];
        float4 vb = b[i];
        float d0 = va.x - vb.x;
        float d1 = va.y - vb.y;
        float d2 = va.z - vb.z;
        float d3 = va.w - vb.w;
        d0 = (fabsf(d0) < ERROR_OK) ? 0.0f : d0;
        d1 = (fabsf(d1) < ERROR_OK) ? 0.0f : d1;
        d2 = (fabsf(d2) < ERROR_OK) ? 0.0f : d2;
        d3 = (fabsf(d3) < ERROR_OK) ? 0.0f : d3;
        acc[0] += d0 * d0 + d1 * d1 + d2 * d2 + d3 * d3;
    }

    float sum = (acc[0] + acc[1]) + (acc[2] + acc[3]);

    // wave-64 butterfly reduce
    #pragma unroll
    for (int off = 32; off > 0; off >>= 1)
        sum += __shfl_down(sum, off, 64);

    __shared__ float smem[BLOCK / 64];
    const int lane = threadIdx.x & 63;
    const int wave = threadIdx.x >> 6;
    if (lane == 0) smem[wave] = sum;
    __syncthreads();

    if (threadIdx.x == 0) {
        float s = 0.0f;
        #pragma unroll
        for (int w = 0; w < BLOCK / 64; ++w) s += smem[w];
        partials[blockIdx.x] = s;
    }
}

// Stage 2: single block reduces GRID partials, scales by 1/N. Deterministic.
__global__ __launch_bounds__(BLOCK) void dz_final_kernel(
    const float* __restrict__ partials,
    float* __restrict__ out,
    int nparts,
    float inv_n)
{
    float sum = 0.0f;
    for (int i = threadIdx.x; i < nparts; i += BLOCK)
        sum += partials[i];

    #pragma unroll
    for (int off = 32; off > 0; off >>= 1)
        sum += __shfl_down(sum, off, 64);

    __shared__ float smem[BLOCK / 64];
    const int lane = threadIdx.x & 63;
    const int wave = threadIdx.x >> 6;
    if (lane == 0) smem[wave] = sum;
    __syncthreads();

    if (threadIdx.x == 0) {
        float s = 0.0f;
        #pragma unroll
        for (int w = 0; w < BLOCK / 64; ++w) s += smem[w];
        out[0] = s * inv_n;
    }
}

extern "C" void kernel_launch(void* const* d_in, const int* in_sizes, int n_in,
                              void* d_out, int out_size, void* d_ws, size_t ws_size,
                              hipStream_t stream) {
    const float4* a = (const float4*)d_in[0];
    const float4* b = (const float4*)d_in[1];
    float* out      = (float*)d_out;
    float* partials = (float*)d_ws;   // GRID floats = 8 KiB scratch

    const int n  = in_sizes[0];       // 33554432, divisible by 4
    const int n4 = n / 4;

    dz_partial_kernel<<<GRID, BLOCK, 0, stream>>>(a, b, partials, n4);
    dz_final_kernel<<<1, BLOCK, 0, stream>>>(partials, out, GRID, 1.0f / (float)n);
}

// Round 3
// 278.624 us; speedup vs baseline: 1.0029x; 1.0029x over previous
//
#include <hip/hip_runtime.h>

#define ERROR_OK 0.1f

constexpr int BLOCK  = 256;
constexpr int GRID   = 2048;   // 8192 waves = exactly HW wave capacity
constexpr int UNROLL = 8;      // 16 x 16B loads in flight per thread

// Stage 1: grid-stride float4 streaming.
// __launch_bounds__(256,4): min 4 waves/SIMD -> 128-VGPR budget. Without this
// the scheduler targets max occupancy, sinks loads into uses (R2: VGPR=24,
// loads serialized, 113us). We WANT ~80-100 VGPRs here so all 16 loads issue
// before the first vmcnt wait.
__global__ __launch_bounds__(BLOCK, 4) void dz_partial_kernel(
    const float4* __restrict__ a,
    const float4* __restrict__ b,
    float* __restrict__ partials,
    int n4)
{
    const int tid    = blockIdx.x * BLOCK + threadIdx.x;
    const int stride = GRID * BLOCK;

    float acc0 = 0.0f, acc1 = 0.0f, acc2 = 0.0f, acc3 = 0.0f;

    int i = tid;
    for (; i + (UNROLL - 1) * stride < n4; i += UNROLL * stride) {
        float4 va[UNROLL], vb[UNROLL];
        // interleave a/b per k: consumption order matches issue order, so the
        // compiler can use partial vmcnt(N) waits and overlap compute with
        // still-outstanding loads
        #pragma unroll
        for (int k = 0; k < UNROLL; ++k) {
            va[k] = a[i + k * stride];
            vb[k] = b[i + k * stride];
        }
        #pragma unroll
        for (int k = 0; k < UNROLL; ++k) {
            float d0 = va[k].x - vb[k].x;
            float d1 = va[k].y - vb[k].y;
            float d2 = va[k].z - vb[k].z;
            float d3 = va[k].w - vb[k].w;
            d0 = (fabsf(d0) < ERROR_OK) ? 0.0f : d0;
            d1 = (fabsf(d1) < ERROR_OK) ? 0.0f : d1;
            d2 = (fabsf(d2) < ERROR_OK) ? 0.0f : d2;
            d3 = (fabsf(d3) < ERROR_OK) ? 0.0f : d3;
            acc0 += d0 * d0;
            acc1 += d1 * d1;
            acc2 += d2 * d2;
            acc3 += d3 * d3;
        }
    }
    // tail (not hit for N=2^25: 16 iters/thread = 2 clean unrolled passes)
    for (; i < n4; i += stride) {
        float4 va = a[i];
        float4 vb = b[i];
        float d0 = va.x - vb.x;
        float d1 = va.y - vb.y;
        float d2 = va.z - vb.z;
        float d3 = va.w - vb.w;
        d0 = (fabsf(d0) < ERROR_OK) ? 0.0f : d0;
        d1 = (fabsf(d1) < ERROR_OK) ? 0.0f : d1;
        d2 = (fabsf(d2) < ERROR_OK) ? 0.0f : d2;
        d3 = (fabsf(d3) < ERROR_OK) ? 0.0f : d3;
        acc0 += d0 * d0;
        acc1 += d1 * d1;
        acc2 += d2 * d2;
        acc3 += d3 * d3;
    }

    float sum = (acc0 + acc1) + (acc2 + acc3);

    // wave-64 butterfly reduce
    #pragma unroll
    for (int off = 32; off > 0; off >>= 1)
        sum += __shfl_down(sum, off, 64);

    __shared__ float smem[BLOCK / 64];
    const int lane = threadIdx.x & 63;
    const int wave = threadIdx.x >> 6;
    if (lane == 0) smem[wave] = sum;
    __syncthreads();

    if (threadIdx.x == 0) {
        float s = 0.0f;
        #pragma unroll
        for (int w = 0; w < BLOCK / 64; ++w) s += smem[w];
        partials[blockIdx.x] = s;
    }
}

// Stage 2: single block reduces GRID partials, scales by 1/N. Deterministic.
__global__ __launch_bounds__(BLOCK) void dz_final_kernel(
    const float* __restrict__ partials,
    float* __restrict__ out,
    int nparts,
    float inv_n)
{
    float sum = 0.0f;
    for (int i = threadIdx.x; i < nparts; i += BLOCK)
        sum += partials[i];

    #pragma unroll
    for (int off = 32; off > 0; off >>= 1)
        sum += __shfl_down(sum, off, 64);

    __shared__ float smem[BLOCK / 64];
    const int lane = threadIdx.x & 63;
    const int wave = threadIdx.x >> 6;
    if (lane == 0) smem[wave] = sum;
    __syncthreads();

    if (threadIdx.x == 0) {
        float s = 0.0f;
        #pragma unroll
        for (int w = 0; w < BLOCK / 64; ++w) s += smem[w];
        out[0] = s * inv_n;
    }
}

extern "C" void kernel_launch(void* const* d_in, const int* in_sizes, int n_in,
                              void* d_out, int out_size, void* d_ws, size_t ws_size,
                              hipStream_t stream) {
    const float4* a = (const float4*)d_in[0];
    const float4* b = (const float4*)d_in[1];
    float* out      = (float*)d_out;
    float* partials = (float*)d_ws;   // GRID floats = 8 KiB scratch

    const int n  = in_sizes[0];       // 33554432, divisible by 4
    const int n4 = n / 4;

    dz_partial_kernel<<<GRID, BLOCK, 0, stream>>>(a, b, partials, n4);
    dz_final_kernel<<<1, BLOCK, 0, stream>>>(partials, out, GRID, 1.0f / (float)n);
}

// Round 4
// 253.342 us; speedup vs baseline: 1.1029x; 1.0998x over previous
//
#include <hip/hip_runtime.h>

#define ERROR_OK 0.1f

constexpr int BLOCK = 256;
constexpr int GRID  = 2048;   // 8192 waves = HW wave capacity

typedef float v4f __attribute__((ext_vector_type(4)));

// Stage 1: grid-stride streaming with NON-TEMPORAL 16B loads.
// R1-R3 all plateau at 2.6 TB/s aggregate read regardless of per-thread MLP
// (VGPR 12 vs 40: identical time) -> per-CU line-granular L1 MSHR cap
// (~64 lines = 4KB in flight / 375ns = 10.7 GB/s/CU = 2.7 TB/s chip — matches).
// nt loads bypass L1 allocation for these single-use streams.
__global__ __launch_bounds__(BLOCK) void dz_partial_kernel(
    const v4f* __restrict__ a,
    const v4f* __restrict__ b,
    float* __restrict__ partials,
    int n4)
{
    const int tid    = blockIdx.x * BLOCK + threadIdx.x;
    const int stride = GRID * BLOCK;

    float sum = 0.0f;
    for (int i = tid; i < n4; i += stride) {
        v4f va = __builtin_nontemporal_load(&a[i]);
        v4f vb = __builtin_nontemporal_load(&b[i]);
        float d0 = va[0] - vb[0];
        float d1 = va[1] - vb[1];
        float d2 = va[2] - vb[2];
        float d3 = va[3] - vb[3];
        d0 = (fabsf(d0) < ERROR_OK) ? 0.0f : d0;
        d1 = (fabsf(d1) < ERROR_OK) ? 0.0f : d1;
        d2 = (fabsf(d2) < ERROR_OK) ? 0.0f : d2;
        d3 = (fabsf(d3) < ERROR_OK) ? 0.0f : d3;
        sum += d0 * d0 + d1 * d1 + d2 * d2 + d3 * d3;
    }

    // wave-64 butterfly reduce
    #pragma unroll
    for (int off = 32; off > 0; off >>= 1)
        sum += __shfl_down(sum, off, 64);

    __shared__ float smem[BLOCK / 64];
    const int lane = threadIdx.x & 63;
    const int wave = threadIdx.x >> 6;
    if (lane == 0) smem[wave] = sum;
    __syncthreads();

    if (threadIdx.x == 0) {
        float s = 0.0f;
        #pragma unroll
        for (int w = 0; w < BLOCK / 64; ++w) s += smem[w];
        partials[blockIdx.x] = s;
    }
}

// Stage 2: single block reduces GRID partials, scales by 1/N. Deterministic.
__global__ __launch_bounds__(BLOCK) void dz_final_kernel(
    const float* __restrict__ partials,
    float* __restrict__ out,
    int nparts,
    float inv_n)
{
    float sum = 0.0f;
    for (int i = threadIdx.x; i < nparts; i += BLOCK)
        sum += partials[i];

    #pragma unroll
    for (int off = 32; off > 0; off >>= 1)
        sum += __shfl_down(sum, off, 64);

    __shared__ float smem[BLOCK / 64];
    const int lane = threadIdx.x & 63;
    const int wave = threadIdx.x >> 6;
    if (lane == 0) smem[wave] = sum;
    __syncthreads();

    if (threadIdx.x == 0) {
        float s = 0.0f;
        #pragma unroll
        for (int w = 0; w < BLOCK / 64; ++w) s += smem[w];
        out[0] = s * inv_n;
    }
}

extern "C" void kernel_launch(void* const* d_in, const int* in_sizes, int n_in,
                              void* d_out, int out_size, void* d_ws, size_t ws_size,
                              hipStream_t stream) {
    const v4f* a    = (const v4f*)d_in[0];
    const v4f* b    = (const v4f*)d_in[1];
    float* out      = (float*)d_out;
    float* partials = (float*)d_ws;   // GRID floats = 8 KiB scratch

    const int n  = in_sizes[0];       // 33554432, divisible by 4
    const int n4 = n / 4;

    dz_partial_kernel<<<GRID, BLOCK, 0, stream>>>(a, b, partials, n4);
    dz_final_kernel<<<1, BLOCK, 0, stream>>>(partials, out, GRID, 1.0f / (float)n);
}